// Round 2
// baseline (417.902 us; speedup 1.0000x reference)
//
#include <hip/hip_runtime.h>
#include <stdint.h>

#define IN_F 4096
#define OUT_F 4096
#define NTOK 8192   // 4 * 2048
#define BM 128
#define BN 128
#define BK 64

typedef int int4v __attribute__((ext_vector_type(4)));

typedef const __attribute__((address_space(1))) void* gas1_t;
typedef __attribute__((address_space(3))) void* gas3_t;

__device__ __forceinline__ void gload_lds16(const int8_t* g, int8_t* l) {
  __builtin_amdgcn_global_load_lds((gas1_t)(const void*)g, (gas3_t)(void*)l, 16, 0, 0);
}

// ---------------------------------------------------------------------------
// Kernel 1: per-token activation quantization.
// One block per token row (4096 f32). Row lives in registers between the
// absmax pass and the quant pass. 256 thr * 16 elems.
// ---------------------------------------------------------------------------
__global__ __launch_bounds__(256) void act_quant_kernel(
    const float* __restrict__ x, int8_t* __restrict__ xq, float* __restrict__ xs)
{
  const int row = blockIdx.x;
  const int t = threadIdx.x;
  const float* xr = x + (size_t)row * IN_F;
  float4 v[4];
  float amax = 0.f;
#pragma unroll
  for (int i = 0; i < 4; ++i) {
    v[i] = reinterpret_cast<const float4*>(xr)[t * 4 + i];
    amax = fmaxf(amax, fmaxf(fmaxf(fabsf(v[i].x), fabsf(v[i].y)),
                             fmaxf(fabsf(v[i].z), fabsf(v[i].w))));
  }
#pragma unroll
  for (int off = 32; off; off >>= 1)
    amax = fmaxf(amax, __shfl_xor(amax, off));
  __shared__ float red[4];
  if ((t & 63) == 0) red[t >> 6] = amax;
  __syncthreads();
  amax = fmaxf(fmaxf(red[0], red[1]), fmaxf(red[2], red[3]));
  // IEEE division to match jnp exactly (no -ffast-math so this stays a divide)
  const float s = amax / 127.0f;
  if (t == 0) xs[row] = s;

  int4v packed;
#pragma unroll
  for (int i = 0; i < 4; ++i) {
    int q0 = (int)rintf(v[i].x / s);
    int q1 = (int)rintf(v[i].y / s);
    int q2 = (int)rintf(v[i].z / s);
    int q3 = (int)rintf(v[i].w / s);
    q0 = max(-128, min(127, q0));
    q1 = max(-128, min(127, q1));
    q2 = max(-128, min(127, q2));
    q3 = max(-128, min(127, q3));
    packed[i] = (q0 & 255) | ((q1 & 255) << 8) | ((q2 & 255) << 16) | (q3 << 24);
  }
  *reinterpret_cast<int4v*>(xq + (size_t)row * IN_F + t * 16) = packed;
}

// ---------------------------------------------------------------------------
// Kernel 2: weight dequant + transpose to WT[N][K] int8.
// Block handles 64 out-cols x 128 in-rows (= exactly one scale group).
// Coalesced qweight reads (along out), transpose through LDS (padded stride),
// coalesced 16B writes of WT rows.
// ---------------------------------------------------------------------------
__global__ __launch_bounds__(256) void wdq_kernel(
    const int* __restrict__ qweight, const int* __restrict__ qzeros,
    const float* __restrict__ scales, int8_t* __restrict__ wt)
{
  __shared__ int8_t tile[64 * 144];   // [o_local][k_local], stride 144 = 16-aligned pad
  const int t = threadIdx.x;
  const int g = blockIdx.x;           // k-tile == group (128 k = 16 qweight rows)
  const int o0 = blockIdx.y * 64;
  const int i0 = g * 16;
  const int ol = t & 63;
  const int o = o0 + ol;

  const int zw = qzeros[g * (OUT_F / 8) + (o >> 3)];
  const int znib = (zw >> ((o & 7) * 4)) & 15;
  const float sc = scales[g * OUT_F + o];

#pragma unroll
  for (int j = 0; j < 4; ++j) {
    const int il = j * 4 + (t >> 6);
    const int w = qweight[(size_t)(i0 + il) * OUT_F + o];
    uint64_t packed = 0;
#pragma unroll
    for (int nb = 0; nb < 8; ++nb) {
      const int wnib = (w >> (nb * 4)) & 15;
      // int8 modular diff: (int8)(w<<4) - (int8)(z<<4) wrapped
      const int8_t diff = (int8_t)(((wnib - znib) & 15) << 4);
      float val = rintf(sc * (float)diff);
      val = fminf(127.f, fmaxf(-128.f, val));
      packed |= (uint64_t)(uint8_t)(int8_t)(int)val << (8 * nb);
    }
    *reinterpret_cast<uint64_t*>(&tile[ol * 144 + il * 8]) = packed;
  }
  __syncthreads();
  const int orow = t >> 2;
  const int kb = (t & 3) * 32;
  int4v w0 = *reinterpret_cast<int4v*>(&tile[orow * 144 + kb]);
  int4v w1 = *reinterpret_cast<int4v*>(&tile[orow * 144 + kb + 16]);
  int8_t* dst = wt + (size_t)(o0 + orow) * IN_F + g * 128 + kb;
  *reinterpret_cast<int4v*>(dst) = w0;
  *reinterpret_cast<int4v*>(dst + 16) = w1;
}

// ---------------------------------------------------------------------------
// Kernel 3: int8 GEMM, m97 structure. 128x128 tile, BK=64, 4 waves (2x2),
// global_load_lds width-16 staging, mfma_i32_16x16x64_i8, fused dequant+bias.
// ---------------------------------------------------------------------------
__global__ __launch_bounds__(256) void gemm_kernel(
    const int8_t* __restrict__ aq, const int8_t* __restrict__ wt,
    const float* __restrict__ xs, const float* __restrict__ int8_scales,
    const float* __restrict__ bias, float* __restrict__ out)
{
  __shared__ int8_t a_lds[BM * BK];   // [m][k] 64B rows
  __shared__ int8_t b_lds[BN * BK];   // [n][k] 64B rows

  // XCD-bijective swizzle (nwg = 2048, divisible by 8)
  int bid = blockIdx.x;
  const int cpx = gridDim.x >> 3;
  bid = (bid & 7) * cpx + (bid >> 3);
  const int mtile = bid >> 5;    // 32 n-tiles
  const int ntile = bid & 31;
  const int m0 = mtile * BM;
  const int n0 = ntile * BN;

  const int t = threadIdx.x;
  const int l = t & 63;
  const int w = t >> 6;
  const int wm = (w >> 1) * 64;
  const int wn = (w & 1) * 64;

  // staging: thread t covers 16B at (row = t/4, byte = (t%4)*16), rounds r=0,1 add 64 rows
  const int lrow = t >> 2;
  const int lbyte = (t & 3) * 16;
  const int8_t* a_src = aq + (size_t)(m0 + lrow) * IN_F + lbyte;
  const int8_t* b_src = wt + (size_t)(n0 + lrow) * IN_F + lbyte;
  int8_t* a_dst = a_lds + t * 16;   // lane-linear => matches gload_lds base+lane*16
  int8_t* b_dst = b_lds + t * 16;

  int4v acc[4][4];
#pragma unroll
  for (int i = 0; i < 4; ++i)
#pragma unroll
    for (int j = 0; j < 4; ++j)
      acc[i][j] = (int4v){0, 0, 0, 0};

  // fragment base (in 16B units): row*4 + (l>>4)
  const int4v* a_fp = reinterpret_cast<const int4v*>(a_lds) + (wm + (l & 15)) * 4 + (l >> 4);
  const int4v* b_fp = reinterpret_cast<const int4v*>(b_lds) + (wn + (l & 15)) * 4 + (l >> 4);

  for (int kt = 0; kt < IN_F / BK; ++kt) {
    const int koff = kt * BK;
    gload_lds16(a_src + koff, a_dst);
    gload_lds16(a_src + (size_t)64 * IN_F + koff, a_dst + 4096);
    gload_lds16(b_src + koff, b_dst);
    gload_lds16(b_src + (size_t)64 * IN_F + koff, b_dst + 4096);
    __syncthreads();   // compiler drains vmcnt before s_barrier

    int4v af[4], bf[4];
#pragma unroll
    for (int i = 0; i < 4; ++i) af[i] = a_fp[i * 64];
#pragma unroll
    for (int j = 0; j < 4; ++j) bf[j] = b_fp[j * 64];
#pragma unroll
    for (int i = 0; i < 4; ++i)
#pragma unroll
      for (int j = 0; j < 4; ++j)
        acc[i][j] = __builtin_amdgcn_mfma_i32_16x16x64_i8(af[i], bf[j], acc[i][j], 0, 0, 0);
    __syncthreads();
  }

  // Epilogue: C/D layout col = l&15, row = (l>>4)*4 + r  (dtype-independent, m89/m101)
  float xsv[4][4];
#pragma unroll
  for (int mf = 0; mf < 4; ++mf)
#pragma unroll
    for (int r = 0; r < 4; ++r)
      xsv[mf][r] = xs[m0 + wm + mf * 16 + (l >> 4) * 4 + r];

#pragma unroll
  for (int nf = 0; nf < 4; ++nf) {
    const int col = n0 + wn + nf * 16 + (l & 15);
    const float is = int8_scales[col];
    const float bv = bias[col];
#pragma unroll
    for (int mf = 0; mf < 4; ++mf) {
      const int rowb = m0 + wm + mf * 16 + (l >> 4) * 4;
#pragma unroll
      for (int r = 0; r < 4; ++r) {
        const float dq = xsv[mf][r] * is;
        out[(size_t)(rowb + r) * OUT_F + col] = (float)acc[mf][nf][r] * dq + bv;
      }
    }
  }
}

// ---------------------------------------------------------------------------
extern "C" void kernel_launch(void* const* d_in, const int* in_sizes, int n_in,
                              void* d_out, int out_size, void* d_ws, size_t ws_size,
                              hipStream_t stream) {
  const float* x           = (const float*)d_in[0];
  const int*   qweight     = (const int*)d_in[1];
  const int*   qzeros      = (const int*)d_in[2];
  const float* scales      = (const float*)d_in[3];
  const float* int8_scales = (const float*)d_in[4];
  const float* bias        = (const float*)d_in[5];
  // d_in[6] = g_idx: always i//128, computed directly in-kernel
  float* out = (float*)d_out;

  // workspace layout: A_q [8192][4096] i8 | WT [4096][4096] i8 | xs [8192] f32
  int8_t* aq = (int8_t*)d_ws;
  int8_t* wt = aq + (size_t)NTOK * IN_F;
  float*  xs = (float*)(wt + (size_t)OUT_F * IN_F);   // total ~50.4 MB

  act_quant_kernel<<<NTOK, 256, 0, stream>>>(x, aq, xs);
  wdq_kernel<<<dim3(IN_F / 128, OUT_F / 64), 256, 0, stream>>>(qweight, qzeros, scales, wt);
  gemm_kernel<<<(NTOK / BM) * (OUT_F / BN), 256, 0, stream>>>(aq, wt, xs, int8_scales, bias, out);
}